// Round 1
// baseline (5620.936 us; speedup 1.0000x reference)
//
#include <hip/hip_runtime.h>
#include <math.h>

#define NN 20000
#define FF 32
#define TT 12
#define HH 64
#define EE 320000
#define OUTD 12

__device__ __forceinline__ float sigmoidf_(float x) { return 1.f / (1.f + expf(-x)); }

// ---------------- preprocessing ----------------

__global__ void deg_init_kernel(float* deg) {
    int i = blockIdx.x * 256 + threadIdx.x;
    if (i < NN) deg[i] = 1.0f;   // self-loop weight 1
}

__global__ void edge_accum_kernel(const int* ei, const float* ea, float* deg, int* cnt) {
    int e = blockIdx.x * 256 + threadIdx.x;
    if (e >= EE) return;
    int d = ei[EE + e];
    float w = ea[e * 2 + 1];
    atomicAdd(&deg[d], w);
    atomicAdd(&cnt[d], 1);
}

__global__ void dinv_kernel(const float* deg, float* dinv) {
    int i = blockIdx.x * 256 + threadIdx.x;
    if (i < NN) dinv[i] = rsqrtf(deg[i]);   // deg >= 1 always (self-loop)
}

// single-wave sequential-chunk exclusive scan over cnt -> rowptr, cursor
__global__ void scan_kernel(const int* cnt, int* rowptr, int* cursor) {
    int lane = threadIdx.x;
    int run = 0;
    for (int base = 0; base < NN; base += 64) {
        int idx = base + lane;
        int c = (idx < NN) ? cnt[idx] : 0;
        int v = c;
        #pragma unroll
        for (int off = 1; off < 64; off <<= 1) {
            int t = __shfl_up(v, off, 64);
            if (lane >= off) v += t;
        }
        int excl = v - c + run;
        if (idx < NN) { rowptr[idx] = excl; cursor[idx] = excl; }
        run += __shfl(v, 63, 64);
    }
    if (lane == 0) rowptr[NN] = run;
}

__global__ void fill_kernel(const int* ei, const float* ea, const float* dinv,
                            int* cursor, int* colIdx, float* valArr) {
    int e = blockIdx.x * 256 + threadIdx.x;
    if (e >= EE) return;
    int s = ei[e], d = ei[EE + e];
    float w = ea[e * 2 + 1];
    int pos = atomicAdd(&cursor[d], 1);
    colIdx[pos] = s;
    valArr[pos] = dinv[s] * w * dinv[d];
}

// x (N,F,T) -> xT (T,N,F), write-coalesced
__global__ void transpose_kernel(const float* x, float* xT) {
    int i = blockIdx.x * 256 + threadIdx.x;
    if (i >= TT * NN * FF) return;
    int f = i & 31;
    int rest = i >> 5;
    int n = rest % NN;
    int t = rest / NN;
    xT[i] = x[n * (FF * TT) + f * TT + t];
}

// ---------------- GCN gather: g = sigmoid(aggregate + bias) ----------------
// one wave per node, lane = feature (H == 64 == wave size)
__global__ void gather_kernel(const float* __restrict__ xw, const float* __restrict__ dinv,
                              const int* __restrict__ rowptr, const int* __restrict__ colIdx,
                              const float* __restrict__ valArr, const float* __restrict__ bg,
                              float* __restrict__ g) {
    int node = blockIdx.x * 4 + (threadIdx.x >> 6);
    int lane = threadIdx.x & 63;
    if (node >= NN) return;
    float di = dinv[node];
    float acc = di * di * xw[node * 64 + lane];   // self loop
    int s = rowptr[node], e = rowptr[node + 1];
    for (int j = s; j < e; ++j) {
        int c = colIdx[j];
        float v = valArr[j];
        acc += v * xw[c * 64 + lane];
    }
    g[node * 64 + lane] = sigmoidf_(acc + bg[lane]);
}

// ---------------- fused GEMM ----------------
// A row n, col k assembled from up to 3 sources: [A1 (width W1) | A2 (64) | A3 (64)]
template<int K, int W1>
__device__ __forceinline__ float fetchA(const float* A1, const float* A2, const float* A3,
                                        int row, int k) {
    if constexpr (K == W1) {
        return A1[row * W1 + k];
    } else {
        if (k < W1) return A1[row * W1 + k];
        else if (k < W1 + 64) return A2[row * 64 + (k - W1)];
        else return A3[row * 64 + (k - W1 - 64)];
    }
}

// EPI 0: out1 = acc                                   (plain, no bias)
// EPI 1: NC=128. cols<64: out1(u)=sig(acc+b1); cols>=64: out2(rh)=sig(acc+b2)*hgate
// EPI 2: NC=64.  c=tanh(acc+b1); hn=u*h+(1-u)*c -> out1 (and hseq_out if non-null)
template<int K, int W1, int NC, int EPI>
__launch_bounds__(256)
__global__ void gemm_kernel(const float* A1, const float* A2, const float* A3,
                            const float* W, const float* W2,
                            const float* b1, const float* b2,
                            const float* hgate, const float* ugate,
                            float* out1, float* out2, float* hseq_out) {
    __shared__ __align__(16) float AsT[32 * 68];   // [k][row], padded stride 68
    __shared__ __align__(16) float Bs[32 * NC];    // [k][col]
    const int tid = threadIdx.x;
    const int tx = tid & 15, ty = tid >> 4;
    const int row0 = blockIdx.x * 64;
    constexpr int CPT = NC / 16;                   // cols per thread: 4 or 8

    float acc[4][CPT];
    #pragma unroll
    for (int i = 0; i < 4; ++i)
        #pragma unroll
        for (int j = 0; j < CPT; ++j) acc[i][j] = 0.f;

    for (int kc = 0; kc < K; kc += 32) {
        // A tile: 64 rows x 32 k, global-coalesced along k, transposed into LDS
        #pragma unroll
        for (int i = 0; i < 8; ++i) {
            int idx = tid + i * 256;
            int kk = idx & 31, rr = idx >> 5;
            int grow = row0 + rr;
            float v = 0.f;
            if (grow < NN) v = fetchA<K, W1>(A1, A2, A3, grow, kc + kk);
            AsT[kk * 68 + rr] = v;
        }
        // B tile: 32 k x NC cols
        if constexpr (NC == 64) {
            #pragma unroll
            for (int i = 0; i < 8; ++i) {
                int idx = tid + i * 256;
                int kk = idx >> 6, cc = idx & 63;
                Bs[kk * 64 + cc] = W[(kc + kk) * 64 + cc];
            }
        } else {
            #pragma unroll
            for (int i = 0; i < 16; ++i) {
                int idx = tid + i * 256;
                int kk = idx >> 7, cc = idx & 127;
                Bs[kk * 128 + cc] = (cc < 64) ? W[(kc + kk) * 64 + cc]
                                              : W2[(kc + kk) * 64 + (cc - 64)];
            }
        }
        __syncthreads();

        #pragma unroll
        for (int k = 0; k < 32; ++k) {
            float4 a4 = *reinterpret_cast<const float4*>(&AsT[k * 68 + ty * 4]);
            float av[4] = {a4.x, a4.y, a4.z, a4.w};
            if constexpr (NC == 64) {
                float4 b4 = *reinterpret_cast<const float4*>(&Bs[k * 64 + tx * 4]);
                float bv[4] = {b4.x, b4.y, b4.z, b4.w};
                #pragma unroll
                for (int i = 0; i < 4; ++i)
                    #pragma unroll
                    for (int j = 0; j < 4; ++j) acc[i][j] += av[i] * bv[j];
            } else {
                float4 b40 = *reinterpret_cast<const float4*>(&Bs[k * 128 + tx * 8]);
                float4 b41 = *reinterpret_cast<const float4*>(&Bs[k * 128 + tx * 8 + 4]);
                float bv[8] = {b40.x, b40.y, b40.z, b40.w, b41.x, b41.y, b41.z, b41.w};
                #pragma unroll
                for (int i = 0; i < 4; ++i)
                    #pragma unroll
                    for (int j = 0; j < 8; ++j) acc[i][j] += av[i] * bv[j];
            }
        }
        __syncthreads();
    }

    // epilogue
    #pragma unroll
    for (int i = 0; i < 4; ++i) {
        int row = row0 + ty * 4 + i;
        if (row >= NN) continue;
        #pragma unroll
        for (int j = 0; j < CPT; ++j) {
            int col = (NC == 64 ? tx * 4 : tx * 8) + j;
            float v = acc[i][j];
            if constexpr (EPI == 0) {
                out1[row * 64 + col] = v;
            } else if constexpr (EPI == 1) {
                if (col < 64) {
                    out1[row * 64 + col] = sigmoidf_(v + b1[col]);
                } else {
                    int cc = col - 64;
                    float r = sigmoidf_(v + b2[cc]);
                    out2[row * 64 + cc] = r * hgate[row * 64 + cc];
                }
            } else {
                float cval = tanhf(v + b1[col]);
                float uu = ugate[row * 64 + col];
                float hh = hgate[row * 64 + col];
                float hn = uu * hh + (1.f - uu) * cval;
                out1[row * 64 + col] = hn;
                if (hseq_out) hseq_out[row * 64 + col] = hn;
            }
        }
    }
}

// ---------------- attention + output head: one wave per node ----------------
__global__ void attention_kernel(const float* __restrict__ hseq,
                                 const float* __restrict__ ipw, const float* __restrict__ ipb,
                                 const float* __restrict__ opw, const float* __restrict__ opb,
                                 const float* __restrict__ ow, const float* __restrict__ ob,
                                 float* __restrict__ out) {
    __shared__ float smem[4 * 3072];
    int wave = threadIdx.x >> 6;
    int lane = threadIdx.x & 63;
    int node = blockIdx.x * 4 + wave;
    float* shh = smem + wave * 3072;         // 768 floats: h, later probs/obar/hattn
    float* shq = smem + wave * 3072 + 768;   // 2304 floats: qkv [t][192]

    // load h_seq[t, node, :]
    #pragma unroll
    for (int t = 0; t < TT; ++t)
        shh[t * 64 + lane] = hseq[((size_t)t * NN + node) * 64 + lane];
    __syncthreads();

    // qkv = h @ in_proj_w.T + b  (12 x 192)
    for (int idx = lane; idx < TT * 192; idx += 64) {
        int t = idx / 192, j = idx % 192;
        float acc = ipb[j];
        const float* wrow = ipw + j * 64;
        const float* hrow = shh + t * 64;
        #pragma unroll
        for (int k = 0; k < 64; ++k) acc += hrow[k] * wrow[k];
        shq[idx] = acc;
    }
    __syncthreads();

    // scores + softmax; probs -> shh[0..288)
    if (lane < 24) {
        int hd = lane / 12, tq = lane % 12;
        const float* qrow = shq + tq * 192 + hd * 32;
        float sc[12];
        float mx = -1e30f;
        #pragma unroll
        for (int s = 0; s < 12; ++s) {
            const float* krow = shq + s * 192 + 64 + hd * 32;
            float a = 0.f;
            #pragma unroll
            for (int d = 0; d < 32; ++d) a += qrow[d] * krow[d];
            a *= 0.17677669529663687f;   // 1/sqrt(32)
            sc[s] = a; mx = fmaxf(mx, a);
        }
        float sum = 0.f;
        #pragma unroll
        for (int s = 0; s < 12; ++s) { sc[s] = expf(sc[s] - mx); sum += sc[s]; }
        float inv = 1.f / sum;
        #pragma unroll
        for (int s = 0; s < 12; ++s) shh[(hd * 12 + tq) * 12 + s] = sc[s] * inv;
    }
    __syncthreads();

    // obar[d] = (1/12) sum_t sum_s p[hd,t,s] * v[s, d] ; mean/out_proj commute
    {
        int d = lane, hd = d >> 5;
        float acc = 0.f;
        #pragma unroll
        for (int s = 0; s < 12; ++s) {
            float ts = 0.f;
            #pragma unroll
            for (int t = 0; t < 12; ++t) ts += shh[(hd * 12 + t) * 12 + s];
            acc += ts * shq[s * 192 + 128 + d];
        }
        shh[300 + d] = acc * (1.f / 12.f);
    }
    __syncthreads();

    // h_attn = obar @ out_proj_w.T + out_proj_b
    {
        int d = lane;
        float acc = opb[d];
        const float* wrow = opw + d * 64;
        #pragma unroll
        for (int k = 0; k < 64; ++k) acc += shh[300 + k] * wrow[k];
        shh[400 + d] = acc;
    }
    __syncthreads();

    // out = h_attn @ out_w + out_b
    if (lane < OUTD) {
        float acc = ob[lane];
        #pragma unroll
        for (int k = 0; k < 64; ++k) acc += shh[400 + k] * ow[k * OUTD + lane];
        out[(size_t)node * OUTD + lane] = acc;
    }
}

// ---------------- launcher ----------------

extern "C" void kernel_launch(void* const* d_in, const int* in_sizes, int n_in,
                              void* d_out, int out_size, void* d_ws, size_t ws_size,
                              hipStream_t stream) {
    const float* x   = (const float*)d_in[0];
    const int*   ei  = (const int*)d_in[1];
    const float* ea  = (const float*)d_in[2];
    const float* Wg0 = (const float*)d_in[3];
    const float* bg0 = (const float*)d_in[4];
    const float* Wu0 = (const float*)d_in[5];
    const float* bu0 = (const float*)d_in[6];
    const float* Wr0 = (const float*)d_in[7];
    const float* br0 = (const float*)d_in[8];
    const float* Wc0 = (const float*)d_in[9];
    const float* bc0 = (const float*)d_in[10];
    const float* Wg1 = (const float*)d_in[11];
    const float* bg1 = (const float*)d_in[12];
    const float* Wu1 = (const float*)d_in[13];
    const float* bu1 = (const float*)d_in[14];
    const float* Wr1 = (const float*)d_in[15];
    const float* br1 = (const float*)d_in[16];
    const float* Wc1 = (const float*)d_in[17];
    const float* bc1 = (const float*)d_in[18];
    const float* ipw = (const float*)d_in[19];
    const float* ipb = (const float*)d_in[20];
    const float* opw = (const float*)d_in[21];
    const float* opb = (const float*)d_in[22];
    const float* ow  = (const float*)d_in[23];
    const float* ob  = (const float*)d_in[24];
    float* out = (float*)d_out;

    char* p = (char*)d_ws;
    auto alloc = [&](size_t bytes) { char* r = p; p += (bytes + 255) & ~(size_t)255; return (void*)r; };
    float* xT     = (float*)alloc((size_t)TT * NN * FF * 4);
    float* deg    = (float*)alloc((size_t)NN * 4);
    float* dinv   = (float*)alloc((size_t)NN * 4);
    int*   cnt    = (int*)  alloc((size_t)NN * 4);
    int*   rowptr = (int*)  alloc((size_t)(NN + 1) * 4);
    int*   cursor = (int*)  alloc((size_t)NN * 4);
    int*   colIdx = (int*)  alloc((size_t)EE * 4);
    float* valArr = (float*)alloc((size_t)EE * 4);
    float* xw     = (float*)alloc((size_t)NN * HH * 4);
    float* g      = (float*)alloc((size_t)NN * HH * 4);
    float* h0     = (float*)alloc((size_t)NN * HH * 4);
    float* h1     = (float*)alloc((size_t)NN * HH * 4);
    float* u      = (float*)alloc((size_t)NN * HH * 4);
    float* rh     = (float*)alloc((size_t)NN * HH * 4);
    float* hseq   = (float*)alloc((size_t)TT * NN * HH * 4);

    hipMemsetAsync(cnt, 0, (size_t)NN * 4, stream);
    hipMemsetAsync(h0, 0, (size_t)NN * HH * 4, stream);
    hipMemsetAsync(h1, 0, (size_t)NN * HH * 4, stream);
    deg_init_kernel<<<(NN + 255) / 256, 256, 0, stream>>>(deg);
    edge_accum_kernel<<<(EE + 255) / 256, 256, 0, stream>>>(ei, ea, deg, cnt);
    dinv_kernel<<<(NN + 255) / 256, 256, 0, stream>>>(deg, dinv);
    scan_kernel<<<1, 64, 0, stream>>>(cnt, rowptr, cursor);
    fill_kernel<<<(EE + 255) / 256, 256, 0, stream>>>(ei, ea, dinv, cursor, colIdx, valArr);
    transpose_kernel<<<(TT * NN * FF + 255) / 256, 256, 0, stream>>>(x, xT);

    const int GB = (NN + 63) / 64;   // 313
    for (int t = 0; t < TT; ++t) {
        const float* xt = xT + (size_t)t * NN * FF;
        // cell 0
        gemm_kernel<32, 32, 64, 0><<<GB, 256, 0, stream>>>(
            xt, nullptr, nullptr, Wg0, nullptr, nullptr, nullptr, nullptr, nullptr,
            xw, nullptr, nullptr);
        gather_kernel<<<NN / 4, 256, 0, stream>>>(xw, dinv, rowptr, colIdx, valArr, bg0, g);
        gemm_kernel<160, 32, 128, 1><<<GB, 256, 0, stream>>>(
            xt, g, h0, Wu0, Wr0, bu0, br0, h0, nullptr,
            u, rh, nullptr);
        gemm_kernel<160, 32, 64, 2><<<GB, 256, 0, stream>>>(
            xt, g, rh, Wc0, nullptr, bc0, nullptr, h0, u,
            h0, nullptr, nullptr);
        // cell 1
        gemm_kernel<64, 64, 64, 0><<<GB, 256, 0, stream>>>(
            h0, nullptr, nullptr, Wg1, nullptr, nullptr, nullptr, nullptr, nullptr,
            xw, nullptr, nullptr);
        gather_kernel<<<NN / 4, 256, 0, stream>>>(xw, dinv, rowptr, colIdx, valArr, bg1, g);
        gemm_kernel<192, 64, 128, 1><<<GB, 256, 0, stream>>>(
            h0, g, h1, Wu1, Wr1, bu1, br1, h1, nullptr,
            u, rh, nullptr);
        gemm_kernel<192, 64, 64, 2><<<GB, 256, 0, stream>>>(
            h0, g, rh, Wc1, nullptr, bc1, nullptr, h1, u,
            h1, nullptr, hseq + (size_t)t * NN * HH);
    }

    attention_kernel<<<NN / 4, 256, 0, stream>>>(hseq, ipw, ipb, opw, opb, ow, ob, out);
}

// Round 2
// 4691.452 us; speedup vs baseline: 1.1981x; 1.1981x over previous
//
#include <hip/hip_runtime.h>
#include <math.h>

#define NN 20000
#define FF 32
#define TT 12
#define HH 64
#define EE 320000
#define OUTD 12

__device__ __forceinline__ float sigmoidf_(float x) { return 1.f / (1.f + expf(-x)); }

// ---------------- preprocessing ----------------

__global__ void deg_init_kernel(float* deg) {
    int i = blockIdx.x * 256 + threadIdx.x;
    if (i < NN) deg[i] = 1.0f;   // self-loop weight 1
}

__global__ void edge_accum_kernel(const int* ei, const float* ea, float* deg, int* cnt) {
    int e = blockIdx.x * 256 + threadIdx.x;
    if (e >= EE) return;
    int d = ei[EE + e];
    float w = ea[e * 2 + 1];
    atomicAdd(&deg[d], w);
    atomicAdd(&cnt[d], 1);
}

__global__ void dinv_kernel(const float* deg, float* dinv) {
    int i = blockIdx.x * 256 + threadIdx.x;
    if (i < NN) dinv[i] = rsqrtf(deg[i]);   // deg >= 1 always (self-loop)
}

// 1024-thread single-block scan: 20 rounds of (wave-scan + cross-wave scan)
__global__ void scan_kernel(const int* cnt, int* rowptr, int* cursor) {
    __shared__ int wsum[16];
    int tid = threadIdx.x;
    int lane = tid & 63, w = tid >> 6;
    int run = 0;
    for (int base = 0; base < NN; base += 1024) {
        int idx = base + tid;
        int c = (idx < NN) ? cnt[idx] : 0;
        int v = c;
        #pragma unroll
        for (int off = 1; off < 64; off <<= 1) {
            int t = __shfl_up(v, off, 64);
            if (lane >= off) v += t;
        }
        if (lane == 63) wsum[w] = v;
        __syncthreads();
        if (tid < 16) {
            int x = wsum[tid];
            #pragma unroll
            for (int off = 1; off < 16; off <<= 1) {
                int t = __shfl_up(x, off, 64);
                if (tid >= off) x += t;
            }
            wsum[tid] = x;
        }
        __syncthreads();
        int waveoff = (w > 0) ? wsum[w - 1] : 0;
        int excl = run + waveoff + (v - c);
        if (idx < NN) { rowptr[idx] = excl; cursor[idx] = excl; }
        run += wsum[15];
        __syncthreads();   // protect wsum before next round's writes
    }
    if (tid == 0) rowptr[NN] = run;
}

__global__ void fill_kernel(const int* ei, const float* ea, const float* dinv,
                            int* cursor, int* colIdx, float* valArr) {
    int e = blockIdx.x * 256 + threadIdx.x;
    if (e >= EE) return;
    int s = ei[e], d = ei[EE + e];
    float w = ea[e * 2 + 1];
    int pos = atomicAdd(&cursor[d], 1);
    colIdx[pos] = s;
    valArr[pos] = dinv[s] * w * dinv[d];
}

// x (N,F,T) -> xT (T,N,F), write-coalesced
__global__ void transpose_kernel(const float* x, float* xT) {
    int i = blockIdx.x * 256 + threadIdx.x;
    if (i >= TT * NN * FF) return;
    int f = i & 31;
    int rest = i >> 5;
    int n = rest % NN;
    int t = rest / NN;
    xT[i] = x[n * (FF * TT) + f * TT + t];
}

// ipw (192,64) -> ipwT (64,192)
__global__ void ipwT_kernel(const float* ipw, float* ipwT) {
    int i = blockIdx.x * 256 + threadIdx.x;
    if (i >= 192 * 64) return;
    int k = i / 192, j = i % 192;
    ipwT[i] = ipw[j * 64 + k];
}

// ---------------- GCN gather: g = sigmoid(aggregate + bias) ----------------
// one wave per node, lane = feature
__global__ void gather_kernel(const float* __restrict__ xw, const float* __restrict__ dinv,
                              const int* __restrict__ rowptr, const int* __restrict__ colIdx,
                              const float* __restrict__ valArr, const float* __restrict__ bg,
                              float* __restrict__ g) {
    int node = blockIdx.x * 4 + (threadIdx.x >> 6);
    int lane = threadIdx.x & 63;
    float di = dinv[node];
    float acc = di * di * xw[node * 64 + lane];   // self loop
    int s = rowptr[node], e = rowptr[node + 1];
    int j = s;
    for (; j + 3 < e; j += 4) {
        int c0 = colIdx[j], c1 = colIdx[j + 1], c2 = colIdx[j + 2], c3 = colIdx[j + 3];
        float v0 = valArr[j], v1 = valArr[j + 1], v2 = valArr[j + 2], v3 = valArr[j + 3];
        float x0 = xw[c0 * 64 + lane], x1 = xw[c1 * 64 + lane];
        float x2 = xw[c2 * 64 + lane], x3 = xw[c3 * 64 + lane];
        acc += v0 * x0 + v1 * x1 + v2 * x2 + v3 * x3;
    }
    for (; j < e; ++j) acc += valArr[j] * xw[colIdx[j] * 64 + lane];
    g[node * 64 + lane] = sigmoidf_(acc + bg[lane]);
}

// ---------------- simple tiled GEMM: out = A(K) @ B[K][NC] (+bias) ----------------
template<int K, int NC, bool HASB>
__launch_bounds__(256)
__global__ void gemm_simple(const float* __restrict__ A, const float* __restrict__ B,
                            const float* __restrict__ bias, float* __restrict__ out,
                            int nrows) {
    __shared__ __align__(16) float AsT[32 * 68];
    __shared__ __align__(16) float Bs[32 * NC];
    const int tid = threadIdx.x;
    const int tx = tid & 15, ty = tid >> 4;
    const int row0 = blockIdx.x * 64;
    constexpr int CPT = NC / 16;

    float acc[4][CPT];
    #pragma unroll
    for (int i = 0; i < 4; ++i)
        #pragma unroll
        for (int j = 0; j < CPT; ++j) acc[i][j] = 0.f;

    for (int kc = 0; kc < K; kc += 32) {
        #pragma unroll
        for (int i = 0; i < 8; ++i) {
            int idx = tid + i * 256;
            int kk = idx & 31, rr = idx >> 5;
            int grow = row0 + rr;
            AsT[kk * 68 + rr] = (grow < nrows) ? A[(size_t)grow * K + kc + kk] : 0.f;
        }
        for (int idx = tid; idx < 32 * NC; idx += 256) {
            int kk = idx / NC, cc = idx % NC;
            Bs[idx] = B[(kc + kk) * NC + cc];
        }
        __syncthreads();
        #pragma unroll
        for (int k = 0; k < 32; ++k) {
            float4 a4 = *reinterpret_cast<const float4*>(&AsT[k * 68 + ty * 4]);
            float av[4] = {a4.x, a4.y, a4.z, a4.w};
            float bv[CPT];
            #pragma unroll
            for (int c = 0; c < CPT / 4; ++c) {
                float4 b4 = *reinterpret_cast<const float4*>(&Bs[k * NC + tx * CPT + c * 4]);
                bv[c * 4 + 0] = b4.x; bv[c * 4 + 1] = b4.y; bv[c * 4 + 2] = b4.z; bv[c * 4 + 3] = b4.w;
            }
            #pragma unroll
            for (int i = 0; i < 4; ++i)
                #pragma unroll
                for (int j = 0; j < CPT; ++j) acc[i][j] += av[i] * bv[j];
        }
        __syncthreads();
    }
    #pragma unroll
    for (int i = 0; i < 4; ++i) {
        int row = row0 + ty * 4 + i;
        if (row >= nrows) continue;
        #pragma unroll
        for (int j = 0; j < CPT; ++j) {
            int col = tx * CPT + j;
            float v = acc[i][j];
            if constexpr (HASB) v += bias[col];
            out[(size_t)row * NC + col] = v;
        }
    }
}

// ---------------- fused GRU cell ----------------
// phase1: [u|r] = sigmoid([A1|g|h] @ [Wu|Wr] + [bu|br])   (u,rh staged in LDS)
// phase3: c = tanh([A1|g|r*h] @ Wc + bc)
// phase4: h_new = u*h + (1-u)*c -> h_out (+hseq)
// PROJ:   xw_out = h_new @ Wnext   (local 64x64 GEMM)
template<int K, int W1, bool PROJ>
__launch_bounds__(256)
__global__ void fused_gru_kernel(const float* __restrict__ A1, const float* __restrict__ g,
                                 const float* h,
                                 const float* __restrict__ Wu, const float* __restrict__ Wr,
                                 const float* __restrict__ Wc,
                                 const float* __restrict__ bu, const float* __restrict__ br,
                                 const float* __restrict__ bc,
                                 const float* __restrict__ Wnext,
                                 float* h_out, float* __restrict__ xw_out,
                                 float* __restrict__ hseq_out) {
    __shared__ __align__(16) float AsT[32 * 68];
    __shared__ __align__(16) float Bs[32 * 128];
    __shared__ __align__(16) float uT[64 * 64];
    __shared__ __align__(16) float rhT[64 * 64];   // later reused as h_new tile
    const int tid = threadIdx.x;
    const int tx = tid & 15, ty = tid >> 4;
    const int row0 = blockIdx.x * 64;

    // ---- phase 1: u|r GEMM (NC=128) ----
    float acc[4][8];
    #pragma unroll
    for (int i = 0; i < 4; ++i)
        #pragma unroll
        for (int j = 0; j < 8; ++j) acc[i][j] = 0.f;

    for (int kc = 0; kc < K; kc += 32) {
        #pragma unroll
        for (int i = 0; i < 8; ++i) {
            int idx = tid + i * 256;
            int kk = idx & 31, rr = idx >> 5;
            int grow = row0 + rr;
            int k = kc + kk;
            float v = 0.f;
            if (grow < NN) {
                if (k < W1) v = A1[(size_t)grow * W1 + k];
                else if (k < W1 + 64) v = g[grow * 64 + (k - W1)];
                else v = h[grow * 64 + (k - W1 - 64)];
            }
            AsT[kk * 68 + rr] = v;
        }
        #pragma unroll
        for (int i = 0; i < 16; ++i) {
            int idx = tid + i * 256;
            int kk = idx >> 7, cc = idx & 127;
            Bs[idx] = (cc < 64) ? Wu[(kc + kk) * 64 + cc] : Wr[(kc + kk) * 64 + (cc - 64)];
        }
        __syncthreads();
        #pragma unroll
        for (int k = 0; k < 32; ++k) {
            float4 a4 = *reinterpret_cast<const float4*>(&AsT[k * 68 + ty * 4]);
            float av[4] = {a4.x, a4.y, a4.z, a4.w};
            float4 b40 = *reinterpret_cast<const float4*>(&Bs[k * 128 + tx * 8]);
            float4 b41 = *reinterpret_cast<const float4*>(&Bs[k * 128 + tx * 8 + 4]);
            float bv[8] = {b40.x, b40.y, b40.z, b40.w, b41.x, b41.y, b41.z, b41.w};
            #pragma unroll
            for (int i = 0; i < 4; ++i)
                #pragma unroll
                for (int j = 0; j < 8; ++j) acc[i][j] += av[i] * bv[j];
        }
        __syncthreads();
    }

    // ---- phase 2: nonlinearity, stage u and r*h in LDS ----
    #pragma unroll
    for (int i = 0; i < 4; ++i) {
        int row = ty * 4 + i;
        int grow = row0 + row;
        #pragma unroll
        for (int j = 0; j < 8; ++j) {
            int col = tx * 8 + j;
            if (col < 64) {
                uT[row * 64 + col] = sigmoidf_(acc[i][j] + bu[col]);
            } else {
                int cc = col - 64;
                float hv = (grow < NN) ? h[grow * 64 + cc] : 0.f;
                rhT[row * 64 + cc] = sigmoidf_(acc[i][j] + br[cc]) * hv;
            }
        }
    }
    __syncthreads();

    // ---- phase 3: c GEMM (NC=64), A-tail from rhT ----
    float acc2[4][4];
    #pragma unroll
    for (int i = 0; i < 4; ++i)
        #pragma unroll
        for (int j = 0; j < 4; ++j) acc2[i][j] = 0.f;

    for (int kc = 0; kc < K; kc += 32) {
        #pragma unroll
        for (int i = 0; i < 8; ++i) {
            int idx = tid + i * 256;
            int kk = idx & 31, rr = idx >> 5;
            int grow = row0 + rr;
            int k = kc + kk;
            float v = 0.f;
            if (k >= W1 + 64) {
                v = rhT[rr * 64 + (k - W1 - 64)];
            } else if (grow < NN) {
                v = (k < W1) ? A1[(size_t)grow * W1 + k] : g[grow * 64 + (k - W1)];
            }
            AsT[kk * 68 + rr] = v;
        }
        #pragma unroll
        for (int i = 0; i < 8; ++i) {
            int idx = tid + i * 256;
            int kk = idx >> 6, cc = idx & 63;
            Bs[idx] = Wc[(kc + kk) * 64 + cc];
        }
        __syncthreads();
        #pragma unroll
        for (int k = 0; k < 32; ++k) {
            float4 a4 = *reinterpret_cast<const float4*>(&AsT[k * 68 + ty * 4]);
            float av[4] = {a4.x, a4.y, a4.z, a4.w};
            float4 b4 = *reinterpret_cast<const float4*>(&Bs[k * 64 + tx * 4]);
            float bv[4] = {b4.x, b4.y, b4.z, b4.w};
            #pragma unroll
            for (int i = 0; i < 4; ++i)
                #pragma unroll
                for (int j = 0; j < 4; ++j) acc2[i][j] += av[i] * bv[j];
        }
        __syncthreads();
    }

    // ---- phase 4: combine, write h_new (rhT reused as h_new tile) ----
    #pragma unroll
    for (int i = 0; i < 4; ++i) {
        int row = ty * 4 + i;
        int grow = row0 + row;
        #pragma unroll
        for (int j = 0; j < 4; ++j) {
            int col = tx * 4 + j;
            float hn = 0.f;
            if (grow < NN) {
                float hv = h[grow * 64 + col];
                float uu = uT[row * 64 + col];
                float cv = tanhf(acc2[i][j] + bc[col]);
                hn = uu * hv + (1.f - uu) * cv;
                h_out[grow * 64 + col] = hn;
                if (hseq_out) hseq_out[grow * 64 + col] = hn;
            }
            rhT[row * 64 + col] = hn;
        }
    }

    // ---- phase 5: fused next projection xw = h_new @ Wnext ----
    if constexpr (PROJ) {
        __syncthreads();
        #pragma unroll
        for (int i = 0; i < 16; ++i) {
            int idx = tid + i * 256;
            Bs[idx] = Wnext[idx];   // 64x64
        }
        __syncthreads();
        float acc3[4][4];
        #pragma unroll
        for (int i = 0; i < 4; ++i)
            #pragma unroll
            for (int j = 0; j < 4; ++j) acc3[i][j] = 0.f;
        #pragma unroll
        for (int k = 0; k < 64; ++k) {
            float av[4];
            #pragma unroll
            for (int i = 0; i < 4; ++i) av[i] = rhT[(ty * 4 + i) * 64 + k];
            float4 b4 = *reinterpret_cast<const float4*>(&Bs[k * 64 + tx * 4]);
            float bv[4] = {b4.x, b4.y, b4.z, b4.w};
            #pragma unroll
            for (int i = 0; i < 4; ++i)
                #pragma unroll
                for (int j = 0; j < 4; ++j) acc3[i][j] += av[i] * bv[j];
        }
        #pragma unroll
        for (int i = 0; i < 4; ++i) {
            int grow = row0 + ty * 4 + i;
            if (grow >= NN) continue;
            #pragma unroll
            for (int j = 0; j < 4; ++j)
                xw_out[grow * 64 + tx * 4 + j] = acc3[i][j];
        }
    }
}

// ---------------- attention core: one wave per node, qkv precomputed ----------------
__global__ void attn_core(const float* __restrict__ qkv,
                          const float* __restrict__ opw, const float* __restrict__ opb,
                          const float* __restrict__ ow, const float* __restrict__ ob,
                          float* __restrict__ out) {
    // per wave: shq[12*196] qkv (padded stride), sp[288] probs, sob[64], sha[64]
    __shared__ float smem[4 * 2768];
    int w = threadIdx.x >> 6;
    int lane = threadIdx.x & 63;
    int node = blockIdx.x * 4 + w;
    float* shq = smem + w * 2768;
    float* sp  = shq + 2352;
    float* sob = shq + 2640;
    float* sha = shq + 2704;

    for (int idx = lane; idx < TT * 192; idx += 64) {
        int t = idx / 192, j = idx - t * 192;
        shq[t * 196 + j] = qkv[((size_t)t * NN + node) * 192 + j];
    }
    __syncthreads();

    if (lane < 24) {
        int hd = lane / 12, tq = lane % 12;
        const float* qrow = shq + tq * 196 + hd * 32;
        float sc[12];
        float mx = -1e30f;
        #pragma unroll
        for (int s = 0; s < 12; ++s) {
            const float* krow = shq + s * 196 + 64 + hd * 32;
            float a = 0.f;
            #pragma unroll
            for (int d = 0; d < 32; ++d) a += qrow[d] * krow[d];
            a *= 0.17677669529663687f;   // 1/sqrt(32)
            sc[s] = a; mx = fmaxf(mx, a);
        }
        float sum = 0.f;
        #pragma unroll
        for (int s = 0; s < 12; ++s) { sc[s] = expf(sc[s] - mx); sum += sc[s]; }
        float inv = 1.f / sum;
        #pragma unroll
        for (int s = 0; s < 12; ++s) sp[(hd * 12 + tq) * 12 + s] = sc[s] * inv;
    }
    __syncthreads();

    // obar[d] = (1/12) sum_s (sum_t p[hd,t,s]) * v[s,d]
    {
        int d = lane, hd = d >> 5;
        float acc = 0.f;
        #pragma unroll
        for (int s = 0; s < 12; ++s) {
            float ts = 0.f;
            #pragma unroll
            for (int t = 0; t < 12; ++t) ts += sp[(hd * 12 + t) * 12 + s];
            acc += ts * shq[s * 196 + 128 + d];
        }
        sob[d] = acc * (1.f / 12.f);
    }
    __syncthreads();

    // h_attn = obar @ out_proj_w.T + out_proj_b
    {
        int d = lane;
        float acc = opb[d];
        const float* wrow = opw + d * 64;
        #pragma unroll
        for (int k = 0; k < 64; ++k) acc += sob[k] * wrow[k];
        sha[d] = acc;
    }
    __syncthreads();

    if (lane < OUTD) {
        float acc = ob[lane];
        #pragma unroll
        for (int k = 0; k < 64; ++k) acc += sha[k] * ow[k * OUTD + lane];
        out[(size_t)node * OUTD + lane] = acc;
    }
}

// ---------------- launcher ----------------

extern "C" void kernel_launch(void* const* d_in, const int* in_sizes, int n_in,
                              void* d_out, int out_size, void* d_ws, size_t ws_size,
                              hipStream_t stream) {
    const float* x   = (const float*)d_in[0];
    const int*   ei  = (const int*)d_in[1];
    const float* ea  = (const float*)d_in[2];
    const float* Wg0 = (const float*)d_in[3];
    const float* bg0 = (const float*)d_in[4];
    const float* Wu0 = (const float*)d_in[5];
    const float* bu0 = (const float*)d_in[6];
    const float* Wr0 = (const float*)d_in[7];
    const float* br0 = (const float*)d_in[8];
    const float* Wc0 = (const float*)d_in[9];
    const float* bc0 = (const float*)d_in[10];
    const float* Wg1 = (const float*)d_in[11];
    const float* bg1 = (const float*)d_in[12];
    const float* Wu1 = (const float*)d_in[13];
    const float* bu1 = (const float*)d_in[14];
    const float* Wr1 = (const float*)d_in[15];
    const float* br1 = (const float*)d_in[16];
    const float* Wc1 = (const float*)d_in[17];
    const float* bc1 = (const float*)d_in[18];
    const float* ipw = (const float*)d_in[19];
    const float* ipb = (const float*)d_in[20];
    const float* opw = (const float*)d_in[21];
    const float* opb = (const float*)d_in[22];
    const float* ow  = (const float*)d_in[23];
    const float* ob  = (const float*)d_in[24];
    float* out = (float*)d_out;

    // ---- workspace: persistent region + union(phase-A loop buffers, qkv) ----
    char* p = (char*)d_ws;
    auto alloc = [&](size_t bytes) { char* r = p; p += (bytes + 255) & ~(size_t)255; return (void*)r; };
    float* hseq = (float*)alloc((size_t)TT * NN * HH * 4);   // persistent
    float* ipwT = (float*)alloc((size_t)64 * 192 * 4);       // persistent
    char* ubase = p;
    // phase-A (t-loop) buffers
    float* xT     = (float*)alloc((size_t)TT * NN * FF * 4);
    float* deg    = (float*)alloc((size_t)NN * 4);
    float* dinv   = (float*)alloc((size_t)NN * 4);
    int*   cnt    = (int*)  alloc((size_t)NN * 4);
    int*   rowptr = (int*)  alloc((size_t)(NN + 1) * 4);
    int*   cursor = (int*)  alloc((size_t)NN * 4);
    int*   colIdx = (int*)  alloc((size_t)EE * 4);
    float* valArr = (float*)alloc((size_t)EE * 4);
    float* xw0all = (float*)alloc((size_t)TT * NN * HH * 4);
    float* g      = (float*)alloc((size_t)NN * HH * 4);
    float* h0a    = (float*)alloc((size_t)NN * HH * 4);
    float* h0b    = (float*)alloc((size_t)NN * HH * 4);
    float* h1a    = (float*)alloc((size_t)NN * HH * 4);
    float* h1b    = (float*)alloc((size_t)NN * HH * 4);
    float* xw1    = (float*)alloc((size_t)NN * HH * 4);
    // phase-B: qkv overlaps all phase-A buffers (dead by the time qkv is written)
    size_t qkv_bytes = (size_t)TT * NN * 192 * 4;
    float* qkv = (float*)ubase;
    char* endA = p;
    char* endB = ubase + ((qkv_bytes + 255) & ~(size_t)255);
    p = (endA > endB) ? endA : endB;
    (void)ws_size;

    hipMemsetAsync(cnt, 0, (size_t)NN * 4, stream);
    hipMemsetAsync(h0a, 0, (size_t)NN * HH * 4, stream);
    hipMemsetAsync(h1a, 0, (size_t)NN * HH * 4, stream);
    deg_init_kernel<<<(NN + 255) / 256, 256, 0, stream>>>(deg);
    edge_accum_kernel<<<(EE + 255) / 256, 256, 0, stream>>>(ei, ea, deg, cnt);
    dinv_kernel<<<(NN + 255) / 256, 256, 0, stream>>>(deg, dinv);
    scan_kernel<<<1, 1024, 0, stream>>>(cnt, rowptr, cursor);
    fill_kernel<<<(EE + 255) / 256, 256, 0, stream>>>(ei, ea, dinv, cursor, colIdx, valArr);
    transpose_kernel<<<(TT * NN * FF + 255) / 256, 256, 0, stream>>>(x, xT);
    ipwT_kernel<<<(192 * 64 + 255) / 256, 256, 0, stream>>>(ipw, ipwT);

    // all 12 cell-0 input projections in one GEMM: (T*N, 32) @ (32, 64)
    gemm_simple<FF, 64, false><<<(TT * NN + 63) / 64, 256, 0, stream>>>(
        xT, Wg0, nullptr, xw0all, TT * NN);

    const int GB = (NN + 63) / 64;   // 313
    for (int t = 0; t < TT; ++t) {
        const float* xt = xT + (size_t)t * NN * FF;
        float* h0_in  = (t & 1) ? h0b : h0a;
        float* h0_out = (t & 1) ? h0a : h0b;
        float* h1_in  = (t & 1) ? h1b : h1a;
        float* h1_out = (t & 1) ? h1a : h1b;
        // cell 0
        gather_kernel<<<NN / 4, 256, 0, stream>>>(
            xw0all + (size_t)t * NN * HH, dinv, rowptr, colIdx, valArr, bg0, g);
        fused_gru_kernel<160, 32, true><<<GB, 256, 0, stream>>>(
            xt, g, h0_in, Wu0, Wr0, Wc0, bu0, br0, bc0, Wg1,
            h0_out, xw1, nullptr);
        // cell 1
        gather_kernel<<<NN / 4, 256, 0, stream>>>(
            xw1, dinv, rowptr, colIdx, valArr, bg1, g);
        fused_gru_kernel<192, 64, false><<<GB, 256, 0, stream>>>(
            h0_out, g, h1_in, Wu1, Wr1, Wc1, bu1, br1, bc1, nullptr,
            h1_out, nullptr, hseq + (size_t)t * NN * HH);
    }

    // qkv = hseq @ ipw.T + ipb : (T*N, 64) @ (64, 192)
    gemm_simple<HH, 192, true><<<(TT * NN + 63) / 64, 256, 0, stream>>>(
        hseq, ipwT, ipb, qkv, TT * NN);

    attn_core<<<NN / 4, 256, 0, stream>>>(qkv, opw, opb, ow, ob, out);
}

// Round 3
// 2536.258 us; speedup vs baseline: 2.2162x; 1.8498x over previous
//
#include <hip/hip_runtime.h>
#include <math.h>

#define NN 20000
#define FF 32
#define TT 12
#define HH 64
#define EE 320000
#define OUTD 12

__device__ __forceinline__ float sigmoidf_(float x) { return 1.f / (1.f + expf(-x)); }

// ---------------- preprocessing ----------------

__global__ void deg_init_kernel(float* deg) {
    int i = blockIdx.x * 256 + threadIdx.x;
    if (i < NN) deg[i] = 1.0f;   // self-loop weight 1
}

__global__ void edge_accum_kernel(const int* ei, const float* ea, float* deg, int* cnt) {
    int e = blockIdx.x * 256 + threadIdx.x;
    if (e >= EE) return;
    int d = ei[EE + e];
    float w = ea[e * 2 + 1];
    atomicAdd(&deg[d], w);
    atomicAdd(&cnt[d], 1);
}

__global__ void dinv_kernel(const float* deg, float* dinv) {
    int i = blockIdx.x * 256 + threadIdx.x;
    if (i < NN) dinv[i] = rsqrtf(deg[i]);
}

// 1024-thread single-block scan
__global__ void scan_kernel(const int* cnt, int* rowptr, int* cursor) {
    __shared__ int wsum[16];
    int tid = threadIdx.x;
    int lane = tid & 63, w = tid >> 6;
    int run = 0;
    for (int base = 0; base < NN; base += 1024) {
        int idx = base + tid;
        int c = (idx < NN) ? cnt[idx] : 0;
        int v = c;
        #pragma unroll
        for (int off = 1; off < 64; off <<= 1) {
            int t = __shfl_up(v, off, 64);
            if (lane >= off) v += t;
        }
        if (lane == 63) wsum[w] = v;
        __syncthreads();
        if (tid < 16) {
            int x = wsum[tid];
            #pragma unroll
            for (int off = 1; off < 16; off <<= 1) {
                int t = __shfl_up(x, off, 64);
                if (tid >= off) x += t;
            }
            wsum[tid] = x;
        }
        __syncthreads();
        int waveoff = (w > 0) ? wsum[w - 1] : 0;
        int excl = run + waveoff + (v - c);
        if (idx < NN) { rowptr[idx] = excl; cursor[idx] = excl; }
        run += wsum[15];
        __syncthreads();
    }
    if (tid == 0) rowptr[NN] = run;
}

__global__ void fill_kernel(const int* ei, const float* ea, const float* dinv,
                            int* cursor, int* colIdx, float* valArr) {
    int e = blockIdx.x * 256 + threadIdx.x;
    if (e >= EE) return;
    int s = ei[e], d = ei[EE + e];
    float w = ea[e * 2 + 1];
    int pos = atomicAdd(&cursor[d], 1);
    colIdx[pos] = s;
    valArr[pos] = dinv[s] * w * dinv[d];
}

// x (N,F,T) -> xT (T,N,F)
__global__ void transpose_kernel(const float* x, float* xT) {
    int i = blockIdx.x * 256 + threadIdx.x;
    if (i >= TT * NN * FF) return;
    int f = i & 31;
    int rest = i >> 5;
    int n = rest % NN;
    int t = rest / NN;
    xT[i] = x[n * (FF * TT) + f * TT + t];
}

// ipw (192,64) -> ipwT (64,192)
__global__ void ipwT_kernel(const float* ipw, float* ipwT) {
    int i = blockIdx.x * 256 + threadIdx.x;
    if (i >= 192 * 64) return;
    int k = i / 192, j = i % 192;
    ipwT[i] = ipw[j * 64 + k];
}

// ---------------- raw normalized aggregation (linear; projection happens after) ----------------
// agg[n][:] = dinv[n]^2 * src[n][:] + sum_e val_e * src[col_e][:]
// W = feature width; blockIdx.y selects an N*W slice (for per-t x slices)
template<int W>
__global__ void gather_raw(const float* __restrict__ srcbase, const float* __restrict__ dinv,
                           const int* __restrict__ rowptr, const int* __restrict__ colIdx,
                           const float* __restrict__ valArr, float* __restrict__ dstbase) {
    const float* src = srcbase + (size_t)blockIdx.y * NN * W;
    float* dst = dstbase + (size_t)blockIdx.y * NN * W;
    int node = blockIdx.x * (256 / W) + threadIdx.x / W;
    int lane = threadIdx.x % W;
    float di = dinv[node];
    float acc = di * di * src[node * W + lane];
    int s = rowptr[node], e = rowptr[node + 1];
    int j = s;
    for (; j + 3 < e; j += 4) {
        int c0 = colIdx[j], c1 = colIdx[j + 1], c2 = colIdx[j + 2], c3 = colIdx[j + 3];
        float v0 = valArr[j], v1 = valArr[j + 1], v2 = valArr[j + 2], v3 = valArr[j + 3];
        acc += v0 * src[c0 * W + lane] + v1 * src[c1 * W + lane]
             + v2 * src[c2 * W + lane] + v3 * src[c3 * W + lane];
    }
    for (; j < e; ++j) acc += valArr[j] * src[colIdx[j] * W + lane];
    dst[node * W + lane] = acc;
}

// ---------------- uniform 64-col tiled GEMM with fused epilogues ----------------
// A row assembled from [A1 (W1) | A2 (64) | A3 (64)] (A2/A3 unused when K==W1).
// B strip selected by blockIdx.y from {B0,B1,B2}, row stride brstride.
// EPI 0: out0 = sigmoid(acc + bias)
// EPI 1: out0[row*ostr + y*64 + col] = acc + bias        (qkv)
// EPI 2: y=0: out0 = sigmoid(acc+bias); y=1: out1 = sigmoid(acc+bias) * hg
// EPI 3: c = tanh(acc+bias); hn = ug*hg + (1-ug)*c -> out0 (+hseq if non-null)
template<int K, int W1, int EPI>
__launch_bounds__(256, 2)
__global__ void gemm64(const float* __restrict__ A1, const float* __restrict__ A2,
                       const float* __restrict__ A3,
                       const float* __restrict__ B0, const float* __restrict__ B1,
                       const float* __restrict__ B2, int brstride,
                       const float* __restrict__ b0, const float* __restrict__ b1,
                       const float* __restrict__ b2,
                       const float* __restrict__ hg, const float* __restrict__ ug,
                       float* __restrict__ out0, float* __restrict__ out1,
                       int ostr, float* __restrict__ hseq, int nrows) {
    __shared__ __align__(16) float AsT[32 * 68];   // [k][row]
    __shared__ __align__(16) float Bs[32 * 68];    // [k][col] padded
    const int tid = threadIdx.x;
    const int tx = tid & 15, ty = tid >> 4;
    const int row0 = blockIdx.x * 64;
    const int y = blockIdx.y;
    const float* B = (y == 0) ? B0 : ((y == 1) ? B1 : B2);
    const float* bias = (y == 0) ? b0 : ((y == 1) ? b1 : b2);

    float acc[4][4];
    #pragma unroll
    for (int i = 0; i < 4; ++i)
        #pragma unroll
        for (int j = 0; j < 4; ++j) acc[i][j] = 0.f;

    for (int kc = 0; kc < K; kc += 32) {
        #pragma unroll
        for (int i = 0; i < 8; ++i) {
            int idx = tid + i * 256;
            int kk = idx & 31, rr = idx >> 5;
            int grow = row0 + rr;
            int k = kc + kk;
            float v = 0.f;
            if (grow < nrows) {
                if constexpr (K == W1) {
                    v = A1[(size_t)grow * W1 + k];
                } else {
                    if (k < W1) v = A1[(size_t)grow * W1 + k];
                    else if (k < W1 + 64) v = A2[grow * 64 + (k - W1)];
                    else v = A3[grow * 64 + (k - W1 - 64)];
                }
            }
            AsT[kk * 68 + rr] = v;
        }
        #pragma unroll
        for (int i = 0; i < 8; ++i) {
            int idx = tid + i * 256;
            int kk = idx >> 6, cc = idx & 63;
            Bs[kk * 68 + cc] = B[(size_t)(kc + kk) * brstride + cc];
        }
        __syncthreads();
        #pragma unroll
        for (int k = 0; k < 32; ++k) {
            float4 a4 = *reinterpret_cast<const float4*>(&AsT[k * 68 + ty * 4]);
            float4 b4 = *reinterpret_cast<const float4*>(&Bs[k * 68 + tx * 4]);
            float av[4] = {a4.x, a4.y, a4.z, a4.w};
            float bv[4] = {b4.x, b4.y, b4.z, b4.w};
            #pragma unroll
            for (int i = 0; i < 4; ++i)
                #pragma unroll
                for (int j = 0; j < 4; ++j) acc[i][j] += av[i] * bv[j];
        }
        __syncthreads();
    }

    #pragma unroll
    for (int i = 0; i < 4; ++i) {
        int row = row0 + ty * 4 + i;
        if (row >= nrows) continue;
        int colb = tx * 4;
        float4 r4;
        float* rv = (float*)&r4;
        if constexpr (EPI == 0) {
            #pragma unroll
            for (int j = 0; j < 4; ++j) rv[j] = sigmoidf_(acc[i][j] + bias[colb + j]);
            *reinterpret_cast<float4*>(&out0[(size_t)row * 64 + colb]) = r4;
        } else if constexpr (EPI == 1) {
            #pragma unroll
            for (int j = 0; j < 4; ++j) rv[j] = acc[i][j] + bias[colb + j];
            *reinterpret_cast<float4*>(&out0[(size_t)row * ostr + y * 64 + colb]) = r4;
        } else if constexpr (EPI == 2) {
            if (y == 0) {
                #pragma unroll
                for (int j = 0; j < 4; ++j) rv[j] = sigmoidf_(acc[i][j] + bias[colb + j]);
                *reinterpret_cast<float4*>(&out0[(size_t)row * 64 + colb]) = r4;
            } else {
                float4 h4 = *reinterpret_cast<const float4*>(&hg[(size_t)row * 64 + colb]);
                const float* hv = (const float*)&h4;
                #pragma unroll
                for (int j = 0; j < 4; ++j)
                    rv[j] = sigmoidf_(acc[i][j] + bias[colb + j]) * hv[j];
                *reinterpret_cast<float4*>(&out1[(size_t)row * 64 + colb]) = r4;
            }
        } else {
            float4 h4 = *reinterpret_cast<const float4*>(&hg[(size_t)row * 64 + colb]);
            float4 u4 = *reinterpret_cast<const float4*>(&ug[(size_t)row * 64 + colb]);
            const float* hv = (const float*)&h4;
            const float* uv = (const float*)&u4;
            #pragma unroll
            for (int j = 0; j < 4; ++j) {
                float cval = tanhf(acc[i][j] + bias[colb + j]);
                rv[j] = uv[j] * hv[j] + (1.f - uv[j]) * cval;
            }
            *reinterpret_cast<float4*>(&out0[(size_t)row * 64 + colb]) = r4;
            if (hseq) *reinterpret_cast<float4*>(&hseq[(size_t)row * 64 + colb]) = r4;
        }
    }
}

// ---------------- attention core: one wave per node, qkv precomputed ----------------
__global__ void attn_core(const float* __restrict__ qkv,
                          const float* __restrict__ opw, const float* __restrict__ opb,
                          const float* __restrict__ ow, const float* __restrict__ ob,
                          float* __restrict__ out) {
    __shared__ float smem[4 * 2768];
    int w = threadIdx.x >> 6;
    int lane = threadIdx.x & 63;
    int node = blockIdx.x * 4 + w;
    float* shq = smem + w * 2768;
    float* sp  = shq + 2352;
    float* sob = shq + 2640;
    float* sha = shq + 2704;

    for (int idx = lane; idx < TT * 192; idx += 64) {
        int t = idx / 192, j = idx - t * 192;
        shq[t * 196 + j] = qkv[((size_t)t * NN + node) * 192 + j];
    }
    __syncthreads();

    if (lane < 24) {
        int hd = lane / 12, tq = lane % 12;
        const float* qrow = shq + tq * 196 + hd * 32;
        float sc[12];
        float mx = -1e30f;
        #pragma unroll
        for (int s = 0; s < 12; ++s) {
            const float* krow = shq + s * 196 + 64 + hd * 32;
            float a = 0.f;
            #pragma unroll
            for (int d = 0; d < 32; ++d) a += qrow[d] * krow[d];
            a *= 0.17677669529663687f;
            sc[s] = a; mx = fmaxf(mx, a);
        }
        float sum = 0.f;
        #pragma unroll
        for (int s = 0; s < 12; ++s) { sc[s] = expf(sc[s] - mx); sum += sc[s]; }
        float inv = 1.f / sum;
        #pragma unroll
        for (int s = 0; s < 12; ++s) sp[(hd * 12 + tq) * 12 + s] = sc[s] * inv;
    }
    __syncthreads();

    {
        int d = lane, hd = d >> 5;
        float acc = 0.f;
        #pragma unroll
        for (int s = 0; s < 12; ++s) {
            float ts = 0.f;
            #pragma unroll
            for (int t = 0; t < 12; ++t) ts += sp[(hd * 12 + t) * 12 + s];
            acc += ts * shq[s * 196 + 128 + d];
        }
        sob[d] = acc * (1.f / 12.f);
    }
    __syncthreads();

    {
        int d = lane;
        float acc = opb[d];
        const float* wrow = opw + d * 64;
        #pragma unroll
        for (int k = 0; k < 64; ++k) acc += sob[k] * wrow[k];
        sha[d] = acc;
    }
    __syncthreads();

    if (lane < OUTD) {
        float acc = ob[lane];
        #pragma unroll
        for (int k = 0; k < 64; ++k) acc += sha[k] * ow[k * OUTD + lane];
        out[(size_t)node * OUTD + lane] = acc;
    }
}

// ---------------- launcher ----------------

extern "C" void kernel_launch(void* const* d_in, const int* in_sizes, int n_in,
                              void* d_out, int out_size, void* d_ws, size_t ws_size,
                              hipStream_t stream) {
    const float* x   = (const float*)d_in[0];
    const int*   ei  = (const int*)d_in[1];
    const float* ea  = (const float*)d_in[2];
    const float* Wg0 = (const float*)d_in[3];
    const float* bg0 = (const float*)d_in[4];
    const float* Wu0 = (const float*)d_in[5];
    const float* bu0 = (const float*)d_in[6];
    const float* Wr0 = (const float*)d_in[7];
    const float* br0 = (const float*)d_in[8];
    const float* Wc0 = (const float*)d_in[9];
    const float* bc0 = (const float*)d_in[10];
    const float* Wg1 = (const float*)d_in[11];
    const float* bg1 = (const float*)d_in[12];
    const float* Wu1 = (const float*)d_in[13];
    const float* bu1 = (const float*)d_in[14];
    const float* Wr1 = (const float*)d_in[15];
    const float* br1 = (const float*)d_in[16];
    const float* Wc1 = (const float*)d_in[17];
    const float* bc1 = (const float*)d_in[18];
    const float* ipw = (const float*)d_in[19];
    const float* ipb = (const float*)d_in[20];
    const float* opw = (const float*)d_in[21];
    const float* opb = (const float*)d_in[22];
    const float* ow  = (const float*)d_in[23];
    const float* ob  = (const float*)d_in[24];
    float* out = (float*)d_out;

    char* p = (char*)d_ws;
    auto alloc = [&](size_t bytes) { char* r = p; p += (bytes + 255) & ~(size_t)255; return (void*)r; };
    // persistent across the whole call
    float* hseq = (float*)alloc((size_t)TT * NN * HH * 4);
    float* ipwT = (float*)alloc((size_t)64 * 192 * 4);
    // union region: loop-phase buffers vs qkv
    char* ubase = p;
    float* xT     = (float*)alloc((size_t)TT * NN * FF * 4);
    float* aggx   = (float*)alloc((size_t)TT * NN * FF * 4);
    float* g0all  = (float*)alloc((size_t)TT * NN * HH * 4);
    float* deg    = (float*)alloc((size_t)NN * 4);
    float* dinv   = (float*)alloc((size_t)NN * 4);
    int*   cnt    = (int*)  alloc((size_t)NN * 4);
    int*   rowptr = (int*)  alloc((size_t)(NN + 1) * 4);
    int*   cursor = (int*)  alloc((size_t)NN * 4);
    int*   colIdx = (int*)  alloc((size_t)EE * 4);
    float* valArr = (float*)alloc((size_t)EE * 4);
    float* aggh   = (float*)alloc((size_t)NN * HH * 4);
    float* g1     = (float*)alloc((size_t)NN * HH * 4);
    float* u      = (float*)alloc((size_t)NN * HH * 4);
    float* rh     = (float*)alloc((size_t)NN * HH * 4);
    float* h0a    = (float*)alloc((size_t)NN * HH * 4);
    float* h0b    = (float*)alloc((size_t)NN * HH * 4);
    float* h1a    = (float*)alloc((size_t)NN * HH * 4);
    float* h1b    = (float*)alloc((size_t)NN * HH * 4);
    size_t qkv_bytes = (size_t)TT * NN * 192 * 4;
    float* qkv = (float*)ubase;
    char* endA = p;
    char* endB = ubase + ((qkv_bytes + 255) & ~(size_t)255);
    p = (endA > endB) ? endA : endB;
    (void)ws_size;

    hipMemsetAsync(cnt, 0, (size_t)NN * 4, stream);
    hipMemsetAsync(h0a, 0, (size_t)NN * HH * 4, stream);
    hipMemsetAsync(h1a, 0, (size_t)NN * HH * 4, stream);
    deg_init_kernel<<<(NN + 255) / 256, 256, 0, stream>>>(deg);
    edge_accum_kernel<<<(EE + 255) / 256, 256, 0, stream>>>(ei, ea, deg, cnt);
    dinv_kernel<<<(NN + 255) / 256, 256, 0, stream>>>(deg, dinv);
    scan_kernel<<<1, 1024, 0, stream>>>(cnt, rowptr, cursor);
    fill_kernel<<<(EE + 255) / 256, 256, 0, stream>>>(ei, ea, dinv, cursor, colIdx, valArr);
    transpose_kernel<<<(TT * NN * FF + 255) / 256, 256, 0, stream>>>(x, xT);
    ipwT_kernel<<<(192 * 64 + 255) / 256, 256, 0, stream>>>(ipw, ipwT);

    // all-t x aggregation (linear GCN trick: aggregate-then-project), one dispatch
    gather_raw<32><<<dim3(NN / 8, TT), 256, 0, stream>>>(xT, dinv, rowptr, colIdx, valArr, aggx);
    // g0 for all t: sigmoid(aggx @ Wg0 + bg0), 240000 rows
    gemm64<32, 32, 0><<<dim3((TT * NN + 63) / 64, 1), 256, 0, stream>>>(
        aggx, nullptr, nullptr, Wg0, nullptr, nullptr, 64, bg0, nullptr, nullptr,
        nullptr, nullptr, g0all, nullptr, 64, nullptr, TT * NN);

    const int GB = (NN + 63) / 64;   // 313
    for (int t = 0; t < TT; ++t) {
        const float* xt = xT + (size_t)t * NN * FF;
        const float* g0 = g0all + (size_t)t * NN * HH;
        float* h0_in  = (t & 1) ? h0b : h0a;
        float* h0_out = (t & 1) ? h0a : h0b;
        float* h1_in  = (t & 1) ? h1b : h1a;
        float* h1_out = (t & 1) ? h1a : h1b;
        // cell 0: u|rh strips, then c/combine
        gemm64<160, 32, 2><<<dim3(GB, 2), 256, 0, stream>>>(
            xt, g0, h0_in, Wu0, Wr0, nullptr, 64, bu0, br0, nullptr,
            h0_in, nullptr, u, rh, 64, nullptr, NN);
        gemm64<160, 32, 3><<<dim3(GB, 1), 256, 0, stream>>>(
            xt, g0, rh, Wc0, nullptr, nullptr, 64, bc0, nullptr, nullptr,
            h0_in, u, h0_out, nullptr, 64, nullptr, NN);
        // cell 1: aggregate h0_new, project+sigmoid, u|rh, c/combine
        gather_raw<64><<<dim3(NN / 4, 1), 256, 0, stream>>>(
            h0_out, dinv, rowptr, colIdx, valArr, aggh);
        gemm64<64, 64, 0><<<dim3(GB, 1), 256, 0, stream>>>(
            aggh, nullptr, nullptr, Wg1, nullptr, nullptr, 64, bg1, nullptr, nullptr,
            nullptr, nullptr, g1, nullptr, 64, nullptr, NN);
        gemm64<192, 64, 2><<<dim3(GB, 2), 256, 0, stream>>>(
            h0_out, g1, h1_in, Wu1, Wr1, nullptr, 64, bu1, br1, nullptr,
            h1_in, nullptr, u, rh, 64, nullptr, NN);
        gemm64<192, 64, 3><<<dim3(GB, 1), 256, 0, stream>>>(
            h0_out, g1, rh, Wc1, nullptr, nullptr, 64, bc1, nullptr, nullptr,
            h1_in, u, h1_out, nullptr, 64, hseq + (size_t)t * NN * HH, NN);
    }

    // qkv = hseq @ ipw.T + ipb : (T*N, 64) @ (64, 192) via 3 column strips
    gemm64<64, 64, 1><<<dim3((TT * NN + 63) / 64, 3), 256, 0, stream>>>(
        hseq, nullptr, nullptr, ipwT, ipwT + 64, ipwT + 128, 192, ipb, ipb + 64, ipb + 128,
        nullptr, nullptr, qkv, nullptr, 192, nullptr, TT * NN);

    attn_core<<<NN / 4, 256, 0, stream>>>(qkv, opw, opb, ow, ob, out);
}